// Round 7
// baseline (696.561 us; speedup 1.0000x reference)
//
#include <hip/hip_runtime.h>
#include <stdint.h>

#define NN 50000   // N_NODES (fixed in reference)
#define NB 196     // ceil(NN/256) scan blocks

typedef unsigned short u16;
typedef _Float16 f16;
typedef __attribute__((ext_vector_type(8))) _Float16 half8;   // MFMA A/B fragment (4 VGPRs)
typedef __attribute__((ext_vector_type(4))) _Float16 half4;
typedef __attribute__((ext_vector_type(4))) float f32x4;

// ---------------- CSR build (dst-sorted adjacency incl. self-loops) ----------------

__global__ void count_k(const int* __restrict__ dst, int* __restrict__ cnt, int E){
  int i = blockIdx.x * 256 + threadIdx.x;
  int tot = E + NN;
  if (i >= tot) return;
  int d = (i < E) ? dst[i] : (i - E);        // self-loop edges appended
  atomicAdd(&cnt[d], 1);
}

// parallel scan, stage 1: per-block (256-wide) sums of cnt
__global__ __launch_bounds__(256) void scan_part_k(const int* __restrict__ cnt,
                                                   int* __restrict__ bsum){
  __shared__ int lds[256];
  int tid = threadIdx.x;
  int idx = blockIdx.x * 256 + tid;
  lds[tid] = (idx < NN) ? cnt[idx] : 0;
  __syncthreads();
#pragma unroll
  for (int off = 128; off >= 1; off >>= 1){
    if (tid < off) lds[tid] += lds[tid + off];
    __syncthreads();
  }
  if (tid == 0) bsum[blockIdx.x] = lds[0];
}

// stage 2: single small block scans the 196 block sums -> exclusive offsets
__global__ __launch_bounds__(256) void scan_top_k(const int* __restrict__ bsum,
                                                  int* __restrict__ boff,
                                                  int* __restrict__ row_ptr){
  __shared__ int lds[256];
  int tid = threadIdx.x;
  int v = (tid < NB) ? bsum[tid] : 0;
  lds[tid] = v;
  __syncthreads();
#pragma unroll
  for (int off = 1; off < 256; off <<= 1){
    int t = (tid >= off) ? lds[tid - off] : 0;
    __syncthreads();
    lds[tid] += t;
    __syncthreads();
  }
  if (tid < NB) boff[tid] = lds[tid] - v;    // exclusive
  if (tid == 255) row_ptr[NN] = lds[255];    // grand total
}

// stage 3: per-block exclusive scan + global offset -> row_ptr / cursor
__global__ __launch_bounds__(256) void scan_fin_k(const int* __restrict__ cnt,
                                                  const int* __restrict__ boff,
                                                  int* __restrict__ row_ptr,
                                                  int* __restrict__ cursor){
  __shared__ int lds[256];
  int tid = threadIdx.x;
  int idx = blockIdx.x * 256 + tid;
  int v = (idx < NN) ? cnt[idx] : 0;
  lds[tid] = v;
  __syncthreads();
#pragma unroll
  for (int off = 1; off < 256; off <<= 1){
    int t = (tid >= off) ? lds[tid - off] : 0;
    __syncthreads();
    lds[tid] += t;
    __syncthreads();
  }
  if (idx < NN){
    int r = boff[blockIdx.x] + lds[tid] - v; // exclusive prefix
    row_ptr[idx] = r;
    cursor[idx]  = r;
  }
}

__global__ void scatter_k(const int* __restrict__ src, const int* __restrict__ dst,
                          int* __restrict__ cursor, int* __restrict__ csr, int E){
  int i = blockIdx.x * 256 + threadIdx.x;
  int tot = E + NN;
  if (i >= tot) return;
  int s, d;
  if (i < E){ s = src[i]; d = dst[i]; } else { s = i - E; d = i - E; }
  int pos = atomicAdd(&cursor[d], 1);
  csr[pos] = s;
}

// -------- W transpose+convert: fp32 [K,N] -> fp16 [N,K] (GEMM B-frags contiguous) ---

__global__ void transpose_k(const float* __restrict__ W, f16* __restrict__ Wt, int K, int N){
  int i = blockIdx.x * 256 + threadIdx.x;
  if (i >= K * N) return;
  int n = i / K, k = i - n * K;
  Wt[i] = (f16)W[k * N + n];                 // write coalesced
}

// ---- LDS-free wide GEMM: C[M,256](fp16) = A[M,K] * B[K,256] --------------------
// One wave owns a 16-row x 256-col strip. A-frag (row m0+l16, 8 contig k) and
// B-frag (Bt row n=i*16+l16, 8 contig k) load straight from global; B is L2-hot
// (<=256 KB). acc[16] f32x4 in registers. No LDS, no barriers.

template<bool A_FP32>
__global__ __launch_bounds__(256) void gemm_direct_k(const void* __restrict__ Aptr,
                                                     const f16* __restrict__ Bt,
                                                     f16* __restrict__ C,
                                                     int M, int K){
  const int wid = blockIdx.x * 4 + (threadIdx.x >> 6);    // global wave id
  const int m0 = wid * 16;
  if (m0 >= M) return;                                    // M % 16 == 0
  const int lane = threadIdx.x & 63;
  const int quad = lane >> 4, l16 = lane & 15;
  const int kq = quad * 8;                                // this lane's k offset

  f32x4 acc[16] = {};

  for (int k0 = 0; k0 < K; k0 += 32){
    half8 af;
    if (A_FP32){
      const float* A = (const float*)Aptr + (size_t)(m0 + l16) * K + k0 + kq;
      const f32x4 f0 = *(const f32x4*)(A);
      const f32x4 f1 = *(const f32x4*)(A + 4);
      af[0] = (f16)f0.x; af[1] = (f16)f0.y; af[2] = (f16)f0.z; af[3] = (f16)f0.w;
      af[4] = (f16)f1.x; af[5] = (f16)f1.y; af[6] = (f16)f1.z; af[7] = (f16)f1.w;
    } else {
      af = *(const half8*)((const f16*)Aptr + (size_t)(m0 + l16) * K + k0 + kq);
    }
#pragma unroll
    for (int i = 0; i < 16; i++){
      half8 bf = *(const half8*)(Bt + (size_t)(i * 16 + l16) * K + k0 + kq);
      acc[i] = __builtin_amdgcn_mfma_f32_16x16x32_f16(af, bf, acc[i], 0, 0, 0);
    }
  }

#pragma unroll
  for (int i = 0; i < 16; i++){
    int n = i * 16 + l16;
#pragma unroll
    for (int r = 0; r < 4; r++){
      int mm = m0 + quad * 4 + r;            // C/D: col=lane&15, row=quad*4+reg
      C[(size_t)mm * 256 + n] = (f16)acc[i][r];
    }
  }
}

// ---- narrow GEMM (layer 3): C[M,N](fp16) = A[M,K]*B[K,N], 64x64 tile, A fp16 ------

__global__ __launch_bounds__(256) void gemm_k(const f16* __restrict__ A,
                                              const f16* __restrict__ Bt,
                                              f16* __restrict__ C,
                                              int M, int N, int K){
  __shared__ f16 As[64 * 40];
  __shared__ f16 Bs[64 * 40];
  const int tid  = threadIdx.x;
  const int wave = tid >> 6, lane = tid & 63;
  const int quad = lane >> 4, l16 = lane & 15;
  const int m0 = blockIdx.x * 64, n0 = blockIdx.y * 64;
  const int srow = tid >> 2;
  const int scol = (tid & 3) * 8;

  f32x4 acc[4] = {};

  for (int k0 = 0; k0 < K; k0 += 32){
    half8 va = {0,0,0,0,0,0,0,0};
    int gm = m0 + srow;
    if (gm < M) va = *(const half8*)(A + (size_t)gm * K + k0 + scol);
    *(half8*)(&As[srow * 40 + scol]) = va;

    half8 vb = {0,0,0,0,0,0,0,0};
    int gn = n0 + srow;
    if (gn < N) vb = *(const half8*)(Bt + (size_t)gn * K + k0 + scol);
    *(half8*)(&Bs[srow * 40 + scol]) = vb;

    __syncthreads();
    half8 af = *(const half8*)(&As[(wave * 16 + l16) * 40 + quad * 8]);
#pragma unroll
    for (int i = 0; i < 4; i++){
      half8 bf = *(const half8*)(&Bs[(i * 16 + l16) * 40 + quad * 8]);
      acc[i] = __builtin_amdgcn_mfma_f32_16x16x32_f16(af, bf, acc[i], 0, 0, 0);
    }
    __syncthreads();
  }

#pragma unroll
  for (int i = 0; i < 4; i++){
    int n = n0 + i * 16 + l16;
#pragma unroll
    for (int r = 0; r < 4; r++){
      int m = m0 + wave * 16 + quad * 4 + r;
      if (m < M && n < N) C[(size_t)m * N + n] = (f16)acc[i][r];
    }
  }
}

// ---------------- attention coefficients (h fp16, att vectors fp32) ----------------

// H=4, C=64: one wave per node; lane owns channels 4l..4l+3 (head = l>>4)
__global__ __launch_bounds__(256) void attn4_k(const f16* __restrict__ h,
                                               const float* __restrict__ atts,
                                               const float* __restrict__ attd,
                                               float* __restrict__ a_s,
                                               float* __restrict__ a_d){
  int w = blockIdx.x * 4 + (threadIdx.x >> 6);
  if (w >= NN) return;
  int lane = threadIdx.x & 63;
  const half4 hv = *(const half4*)(h + (size_t)w * 256 + lane * 4);
  const f32x4 sv = *(const f32x4*)(atts + lane * 4);
  const f32x4 dv = *(const f32x4*)(attd + lane * 4);
  float h0 = (float)hv.x, h1 = (float)hv.y, h2 = (float)hv.z, h3 = (float)hv.w;
  float ps = h0 * sv.x + h1 * sv.y + h2 * sv.z + h3 * sv.w;
  float pd = h0 * dv.x + h1 * dv.y + h2 * dv.z + h3 * dv.w;
#pragma unroll
  for (int off = 8; off >= 1; off >>= 1){    // reduce within 16-lane head group
    ps += __shfl_xor(ps, off);
    pd += __shfl_xor(pd, off);
  }
  if ((lane & 15) == 0){
    a_s[w * 4 + (lane >> 4)] = ps;
    a_d[w * 4 + (lane >> 4)] = pd;
  }
}

// H=1, C=40
__global__ __launch_bounds__(256) void attn1_k(const f16* __restrict__ h,
                                               const float* __restrict__ atts,
                                               const float* __restrict__ attd,
                                               float* __restrict__ a_s,
                                               float* __restrict__ a_d){
  int w = blockIdx.x * 4 + (threadIdx.x >> 6);
  if (w >= NN) return;
  int lane = threadIdx.x & 63;
  float ps = 0.f, pd = 0.f;
  if (lane < 40){
    float hv = (float)h[(size_t)w * 40 + lane];
    ps = hv * atts[lane];
    pd = hv * attd[lane];
  }
#pragma unroll
  for (int off = 32; off >= 1; off >>= 1){
    ps += __shfl_xor(ps, off);
    pd += __shfl_xor(pd, off);
  }
  if (lane == 0){ a_s[w] = ps; a_d[w] = pd; }
}

// ---- edge softmax + aggregate: PAIRWISE online softmax, 2-deep prefetch -----------

__device__ __forceinline__ float lrelu(float e){ return e > 0.f ? e : 0.2f * e; }

// H=4, C=64 -> out[N,256](fp16) = ELU(softmax-agg + bias), feeds next GEMM
__global__ __launch_bounds__(256) void agg4_k(const f16* __restrict__ h,
                                              const float* __restrict__ a_s,
                                              const float* __restrict__ a_d,
                                              const int* __restrict__ row_ptr,
                                              const int* __restrict__ csr,
                                              const float* __restrict__ bias,
                                              f16* __restrict__ out){
  int w = blockIdx.x * 4 + (threadIdx.x >> 6);
  if (w >= NN) return;
  int lane = threadIdx.x & 63;
  int head = lane >> 4;
  float ad = a_d[w * 4 + head];
  int beg = row_ptr[w], end = row_ptr[w + 1];

  float m = -1e30f, denom = 0.f;
  float acc0 = 0.f, acc1 = 0.f, acc2 = 0.f, acc3 = 0.f;

  // preload first pair (clamped)
  int s0 = csr[beg];
  int s1 = csr[(beg + 1 < end) ? beg + 1 : beg];
  float e0 = a_s[s0 * 4 + head];
  float e1 = a_s[s1 * 4 + head];
  half4 h0 = *(const half4*)(h + (size_t)s0 * 256 + lane * 4);
  half4 h1 = *(const half4*)(h + (size_t)s1 * 256 + lane * 4);

  for (int j = beg; j < end; j += 2){
    // prefetch next pair (clamped to already-covered indices at the tail)
    int t0 = (j + 2 < end) ? j + 2 : j;
    int t1 = (j + 3 < end) ? j + 3 : j;
    int sp0 = csr[t0], sp1 = csr[t1];
    float ep0 = a_s[sp0 * 4 + head];
    float ep1 = a_s[sp1 * 4 + head];
    half4 hp0 = *(const half4*)(h + (size_t)sp0 * 256 + lane * 4);
    half4 hp1 = *(const half4*)(h + (size_t)sp1 * 256 + lane * 4);

    float ee0 = lrelu(e0 + ad);
    float ee1 = (j + 1 < end) ? lrelu(e1 + ad) : -1e30f;   // mask odd tail
    float mn = fmaxf(m, fmaxf(ee0, ee1));
    float cold = __expf(m - mn);                            // first iter: 0
    float al0 = __expf(ee0 - mn);
    float al1 = __expf(ee1 - mn);                           // masked -> 0
    denom = denom * cold + al0 + al1;
    acc0 = acc0 * cold + al0 * (float)h0.x + al1 * (float)h1.x;
    acc1 = acc1 * cold + al0 * (float)h0.y + al1 * (float)h1.y;
    acc2 = acc2 * cold + al0 * (float)h0.z + al1 * (float)h1.z;
    acc3 = acc3 * cold + al0 * (float)h0.w + al1 * (float)h1.w;
    m = mn;
    e0 = ep0; e1 = ep1; h0 = hp0; h1 = hp1;
  }

  float inv = 1.f / fmaxf(denom, 1e-30f);    // >=1 edge guaranteed (self-loop)
  float o0 = acc0 * inv + bias[lane * 4 + 0];
  float o1 = acc1 * inv + bias[lane * 4 + 1];
  float o2 = acc2 * inv + bias[lane * 4 + 2];
  float o3 = acc3 * inv + bias[lane * 4 + 3];
  o0 = o0 > 0.f ? o0 : __expf(o0) - 1.f;     // ELU
  o1 = o1 > 0.f ? o1 : __expf(o1) - 1.f;
  o2 = o2 > 0.f ? o2 : __expf(o2) - 1.f;
  o3 = o3 > 0.f ? o3 : __expf(o3) - 1.f;
  half4 r; r.x = (f16)o0; r.y = (f16)o1; r.z = (f16)o2; r.w = (f16)o3;
  *(half4*)(out + (size_t)w * 256 + lane * 4) = r;
}

// H=1, C=40 -> out[N,40](fp32) -> d_out, no ELU
__global__ __launch_bounds__(256) void agg1_k(const f16* __restrict__ h,
                                              const float* __restrict__ a_s,
                                              const float* __restrict__ a_d,
                                              const int* __restrict__ row_ptr,
                                              const int* __restrict__ csr,
                                              const float* __restrict__ bias,
                                              float* __restrict__ out){
  int w = blockIdx.x * 4 + (threadIdx.x >> 6);
  if (w >= NN) return;
  int lane = threadIdx.x & 63;
  int cl = (lane < 40) ? lane : 0;
  float ad = a_d[w];
  int beg = row_ptr[w], end = row_ptr[w + 1];

  float m = -1e30f, denom = 0.f, acc = 0.f;

  int s0 = csr[beg];
  int s1 = csr[(beg + 1 < end) ? beg + 1 : beg];
  float e0 = a_s[s0];
  float e1 = a_s[s1];
  float h0 = (float)h[(size_t)s0 * 40 + cl];
  float h1 = (float)h[(size_t)s1 * 40 + cl];

  for (int j = beg; j < end; j += 2){
    int t0 = (j + 2 < end) ? j + 2 : j;
    int t1 = (j + 3 < end) ? j + 3 : j;
    int sp0 = csr[t0], sp1 = csr[t1];
    float ep0 = a_s[sp0];
    float ep1 = a_s[sp1];
    float hp0 = (float)h[(size_t)sp0 * 40 + cl];
    float hp1 = (float)h[(size_t)sp1 * 40 + cl];

    float ee0 = lrelu(e0 + ad);
    float ee1 = (j + 1 < end) ? lrelu(e1 + ad) : -1e30f;
    float mn = fmaxf(m, fmaxf(ee0, ee1));
    float cold = __expf(m - mn);
    float al0 = __expf(ee0 - mn);
    float al1 = __expf(ee1 - mn);
    denom = denom * cold + al0 + al1;
    acc = acc * cold + al0 * h0 + al1 * h1;
    m = mn;
    e0 = ep0; e1 = ep1; h0 = hp0; h1 = hp1;
  }

  if (lane < 40){
    float o = acc / fmaxf(denom, 1e-30f) + bias[lane];
    out[(size_t)w * 40 + lane] = o;
  }
}

// ---------------- driver -----------------------------------------------------------

extern "C" void kernel_launch(void* const* d_in, const int* in_sizes, int n_in,
                              void* d_out, int out_size, void* d_ws, size_t ws_size,
                              hipStream_t stream){
  const float* x   = (const float*)d_in[0];
  const int*   ei  = (const int*)d_in[1];
  const float* W1  = (const float*)d_in[2];
  const float* as1 = (const float*)d_in[3];
  const float* ad1 = (const float*)d_in[4];
  const float* b1  = (const float*)d_in[5];
  const float* W2  = (const float*)d_in[6];
  const float* as2 = (const float*)d_in[7];
  const float* ad2 = (const float*)d_in[8];
  const float* b2  = (const float*)d_in[9];
  const float* W3  = (const float*)d_in[10];
  const float* as3 = (const float*)d_in[11];
  const float* ad3 = (const float*)d_in[12];
  const float* b3  = (const float*)d_in[13];

  const int E = in_sizes[1] / 2;             // 800000
  const int ETOT = E + NN;
  const int* src_arr = ei;
  const int* dst_arr = ei + E;

  char* ws = (char*)d_ws;
  size_t off = 0;
  auto alloc = [&](size_t bytes) -> void* {
    void* p = ws + off; off += (bytes + 255) & ~(size_t)255; return p;
  };
  int*   cnt     = (int*)  alloc((size_t)NN * 4);
  int*   row_ptr = (int*)  alloc((size_t)(NN + 1) * 4);
  int*   cursor  = (int*)  alloc((size_t)NN * 4);
  int*   csr     = (int*)  alloc((size_t)ETOT * 4);
  int*   bsum    = (int*)  alloc((size_t)256 * 4);
  int*   boff    = (int*)  alloc((size_t)256 * 4);
  f16*   W1t     = (f16*)  alloc((size_t)512 * 256 * 2);
  f16*   W2t     = (f16*)  alloc((size_t)256 * 256 * 2);
  f16*   W3t     = (f16*)  alloc((size_t)256 * 40 * 2);
  float* a_s     = (float*)alloc((size_t)NN * 4 * 4);
  float* a_d     = (float*)alloc((size_t)NN * 4 * 4);
  f16*   hbuf    = (f16*)  alloc((size_t)NN * 256 * 2);   // fp16 h (per-layer)
  f16*   xbuf    = (f16*)  alloc((size_t)NN * 256 * 2);   // fp16 inter-layer activations
  (void)ws_size; (void)n_in; (void)out_size;

  // CSR build (same graph reused by all 3 layers)
  hipMemsetAsync(cnt, 0, (size_t)NN * 4, stream);
  int egrid = (ETOT + 255) / 256;
  count_k    <<<egrid, 256, 0, stream>>>(dst_arr, cnt, E);
  scan_part_k<<<NB, 256, 0, stream>>>(cnt, bsum);
  scan_top_k <<<1, 256, 0, stream>>>(bsum, boff, row_ptr);
  scan_fin_k <<<NB, 256, 0, stream>>>(cnt, boff, row_ptr, cursor);
  scatter_k  <<<egrid, 256, 0, stream>>>(src_arr, dst_arr, cursor, csr, E);

  // weight transposes (fp32 -> fp16)
  transpose_k<<<(512 * 256 + 255) / 256, 256, 0, stream>>>(W1, W1t, 512, 256);
  transpose_k<<<(256 * 256 + 255) / 256, 256, 0, stream>>>(W2, W2t, 256, 256);
  transpose_k<<<(256 * 40  + 255) / 256, 256, 0, stream>>>(W3, W3t, 256, 40);

  dim3 blk(256);
  dim3 gD((NN / 16 + 3) / 4);                // direct GEMM: 1 wave per 16 rows
  dim3 gC((NN + 63) / 64, 1);                // narrow GEMM layer 3 (N=40)
  int nodeblocks = (NN + 3) / 4;             // 12500, one wave per node

  // Layer 1: A = x (fp32), K=512
  gemm_direct_k<true> <<<gD, blk, 0, stream>>>(x, W1t, hbuf, NN, 512);
  attn4_k<<<nodeblocks, blk, 0, stream>>>(hbuf, as1, ad1, a_s, a_d);
  agg4_k <<<nodeblocks, blk, 0, stream>>>(hbuf, a_s, a_d, row_ptr, csr, b1, xbuf);

  // Layer 2: A = xbuf (fp16), K=256
  gemm_direct_k<false><<<gD, blk, 0, stream>>>(xbuf, W2t, hbuf, NN, 256);
  attn4_k<<<nodeblocks, blk, 0, stream>>>(hbuf, as2, ad2, a_s, a_d);
  agg4_k <<<nodeblocks, blk, 0, stream>>>(hbuf, a_s, a_d, row_ptr, csr, b2, xbuf);

  // Layer 3 (H=1, C=40) -> d_out (fp32)
  gemm_k<<<gC, blk, 0, stream>>>(xbuf, W3t, hbuf, NN, 40, 256);
  attn1_k<<<nodeblocks, blk, 0, stream>>>(hbuf, as3, ad3, a_s, a_d);
  agg1_k <<<nodeblocks, blk, 0, stream>>>(hbuf, a_s, a_d, row_ptr, csr, b3, (float*)d_out);
}

// Round 8
// 562.642 us; speedup vs baseline: 1.2380x; 1.2380x over previous
//
#include <hip/hip_runtime.h>
#include <stdint.h>

#define NN 50000   // N_NODES (fixed in reference)
#define NB 196     // ceil(NN/256) scan blocks

typedef unsigned short u16;
typedef _Float16 f16;
typedef __attribute__((ext_vector_type(8))) _Float16 half8;   // MFMA A/B fragment (4 VGPRs)
typedef __attribute__((ext_vector_type(4))) _Float16 half4;
typedef __attribute__((ext_vector_type(4))) float f32x4;

// ---------------- CSR build (dst-sorted adjacency incl. self-loops) ----------------

__global__ void count_k(const int* __restrict__ dst, int* __restrict__ cnt, int E){
  int i = blockIdx.x * 256 + threadIdx.x;
  int tot = E + NN;
  if (i >= tot) return;
  int d = (i < E) ? dst[i] : (i - E);        // self-loop edges appended
  atomicAdd(&cnt[d], 1);
}

// parallel scan, stage 1: per-block (256-wide) sums of cnt
__global__ __launch_bounds__(256) void scan_part_k(const int* __restrict__ cnt,
                                                   int* __restrict__ bsum){
  __shared__ int lds[256];
  int tid = threadIdx.x;
  int idx = blockIdx.x * 256 + tid;
  lds[tid] = (idx < NN) ? cnt[idx] : 0;
  __syncthreads();
#pragma unroll
  for (int off = 128; off >= 1; off >>= 1){
    if (tid < off) lds[tid] += lds[tid + off];
    __syncthreads();
  }
  if (tid == 0) bsum[blockIdx.x] = lds[0];
}

// stage 2: single small block scans the 196 block sums -> exclusive offsets
__global__ __launch_bounds__(256) void scan_top_k(const int* __restrict__ bsum,
                                                  int* __restrict__ boff,
                                                  int* __restrict__ row_ptr){
  __shared__ int lds[256];
  int tid = threadIdx.x;
  int v = (tid < NB) ? bsum[tid] : 0;
  lds[tid] = v;
  __syncthreads();
#pragma unroll
  for (int off = 1; off < 256; off <<= 1){
    int t = (tid >= off) ? lds[tid - off] : 0;
    __syncthreads();
    lds[tid] += t;
    __syncthreads();
  }
  if (tid < NB) boff[tid] = lds[tid] - v;    // exclusive
  if (tid == 255) row_ptr[NN] = lds[255];    // grand total
}

// stage 3: per-block exclusive scan + global offset -> row_ptr / cursor
__global__ __launch_bounds__(256) void scan_fin_k(const int* __restrict__ cnt,
                                                  const int* __restrict__ boff,
                                                  int* __restrict__ row_ptr,
                                                  int* __restrict__ cursor){
  __shared__ int lds[256];
  int tid = threadIdx.x;
  int idx = blockIdx.x * 256 + tid;
  int v = (idx < NN) ? cnt[idx] : 0;
  lds[tid] = v;
  __syncthreads();
#pragma unroll
  for (int off = 1; off < 256; off <<= 1){
    int t = (tid >= off) ? lds[tid - off] : 0;
    __syncthreads();
    lds[tid] += t;
    __syncthreads();
  }
  if (idx < NN){
    int r = boff[blockIdx.x] + lds[tid] - v; // exclusive prefix
    row_ptr[idx] = r;
    cursor[idx]  = r;
  }
}

__global__ void scatter_k(const int* __restrict__ src, const int* __restrict__ dst,
                          int* __restrict__ cursor, int* __restrict__ csr, int E){
  int i = blockIdx.x * 256 + threadIdx.x;
  int tot = E + NN;
  if (i >= tot) return;
  int s, d;
  if (i < E){ s = src[i]; d = dst[i]; } else { s = i - E; d = i - E; }
  int pos = atomicAdd(&cursor[d], 1);
  csr[pos] = s;
}

// -------- W transpose+convert: fp32 [K,N] -> fp16 [N,K] (GEMM B-frags contiguous) ---

__global__ void transpose_k(const float* __restrict__ W, f16* __restrict__ Wt, int K, int N){
  int i = blockIdx.x * 256 + threadIdx.x;
  if (i >= K * N) return;
  int n = i / K, k = i - n * K;
  Wt[i] = (f16)W[k * N + n];                 // write coalesced
}

// ---- m97-style tiled GEMM: C[M,N](fp16) = A[M,K]*B[K,N], Bt fp16 [N,K] ------------
// 128x128 block tile, 4 waves in 2x2, each wave 64x64 (4x4 16x16 MFMA tiles).
// LDS is FRAGMENT-MAJOR: chunk index = mt*64 + (quad*16+l16); lane l of a wave
// reads base + l*16B -> sequential, conflict-free; staging writes are a
// permutation of distinct 16B chunks -> also conflict-free.
// Per K-step per wave: 8 ds_read_b128 + 16 MFMA (minimum LDS:MFMA ratio).

template<bool A_FP32>
__global__ __launch_bounds__(256) void gemm_tile_k(const void* __restrict__ Aptr,
                                                   const f16* __restrict__ Bt,
                                                   f16* __restrict__ C,
                                                   int M, int N, int K){
  __shared__ f16 As[128 * 32];               // [mt 0..7][chunk c 0..3][l16][8]
  __shared__ f16 Bs[128 * 32];
  const int tid  = threadIdx.x;
  const int wave = tid >> 6, lane = tid & 63;
  const int quad = lane >> 4, l16 = lane & 15;
  const int wm = wave >> 1, wn = wave & 1;   // 2x2 wave grid
  const int m0 = blockIdx.x * 128, n0 = blockIdx.y * 128;
  const int srow = tid >> 2;                 // 0..63 staging row
  const int sc   = tid & 3;                  // k-chunk 0..3

  f32x4 acc[4][4] = {};

  for (int k0 = 0; k0 < K; k0 += 32){
    // stage A: 128 rows x 32 k (fp32 path fuses the f16 convert)
#pragma unroll
    for (int rep = 0; rep < 2; rep++){
      int row = rep * 64 + srow;
      int gm = m0 + row;
      half8 va = {0,0,0,0,0,0,0,0};
      if (gm < M){
        if (A_FP32){
          const float* A = (const float*)Aptr + (size_t)gm * K + k0 + sc * 8;
          const f32x4 f0 = *(const f32x4*)(A);
          const f32x4 f1 = *(const f32x4*)(A + 4);
          va[0] = (f16)f0.x; va[1] = (f16)f0.y; va[2] = (f16)f0.z; va[3] = (f16)f0.w;
          va[4] = (f16)f1.x; va[5] = (f16)f1.y; va[6] = (f16)f1.z; va[7] = (f16)f1.w;
        } else {
          va = *(const half8*)((const f16*)Aptr + (size_t)gm * K + k0 + sc * 8);
        }
      }
      *(half8*)(&As[(((row >> 4) * 64) + sc * 16 + (row & 15)) * 8]) = va;
    }
    // stage B: 128 cols x 32 k (N % 128 == 0 for callers)
#pragma unroll
    for (int rep = 0; rep < 2; rep++){
      int row = rep * 64 + srow;
      half8 vb = *(const half8*)(Bt + (size_t)(n0 + row) * K + k0 + sc * 8);
      *(half8*)(&Bs[(((row >> 4) * 64) + sc * 16 + (row & 15)) * 8]) = vb;
    }

    __syncthreads();
    half8 af[4], bf[4];
#pragma unroll
    for (int i = 0; i < 4; i++)
      af[i] = *(const half8*)(&As[((wm * 4 + i) * 64 + lane) * 8]);
#pragma unroll
    for (int j = 0; j < 4; j++)
      bf[j] = *(const half8*)(&Bs[((wn * 4 + j) * 64 + lane) * 8]);
#pragma unroll
    for (int i = 0; i < 4; i++)
#pragma unroll
      for (int j = 0; j < 4; j++)
        acc[i][j] = __builtin_amdgcn_mfma_f32_16x16x32_f16(af[i], bf[j], acc[i][j], 0, 0, 0);
    __syncthreads();
  }

#pragma unroll
  for (int i = 0; i < 4; i++){
#pragma unroll
    for (int j = 0; j < 4; j++){
      int n = n0 + (wn * 4 + j) * 16 + l16;
#pragma unroll
      for (int r = 0; r < 4; r++){
        int mm = m0 + (wm * 4 + i) * 16 + quad * 4 + r;  // C/D: col=l16, row=quad*4+reg
        if (mm < M) C[(size_t)mm * N + n] = (f16)acc[i][j][r];
      }
    }
  }
}

// ---- narrow GEMM (layer 3): C[M,N](fp16) = A[M,K]*B[K,N], 64x64 tile, A fp16 ------

__global__ __launch_bounds__(256) void gemm_k(const f16* __restrict__ A,
                                              const f16* __restrict__ Bt,
                                              f16* __restrict__ C,
                                              int M, int N, int K){
  __shared__ f16 As[64 * 40];
  __shared__ f16 Bs[64 * 40];
  const int tid  = threadIdx.x;
  const int wave = tid >> 6, lane = tid & 63;
  const int quad = lane >> 4, l16 = lane & 15;
  const int m0 = blockIdx.x * 64, n0 = blockIdx.y * 64;
  const int srow = tid >> 2;
  const int scol = (tid & 3) * 8;

  f32x4 acc[4] = {};

  for (int k0 = 0; k0 < K; k0 += 32){
    half8 va = {0,0,0,0,0,0,0,0};
    int gm = m0 + srow;
    if (gm < M) va = *(const half8*)(A + (size_t)gm * K + k0 + scol);
    *(half8*)(&As[srow * 40 + scol]) = va;

    half8 vb = {0,0,0,0,0,0,0,0};
    int gn = n0 + srow;
    if (gn < N) vb = *(const half8*)(Bt + (size_t)gn * K + k0 + scol);
    *(half8*)(&Bs[srow * 40 + scol]) = vb;

    __syncthreads();
    half8 af = *(const half8*)(&As[(wave * 16 + l16) * 40 + quad * 8]);
#pragma unroll
    for (int i = 0; i < 4; i++){
      half8 bf = *(const half8*)(&Bs[(i * 16 + l16) * 40 + quad * 8]);
      acc[i] = __builtin_amdgcn_mfma_f32_16x16x32_f16(af, bf, acc[i], 0, 0, 0);
    }
    __syncthreads();
  }

#pragma unroll
  for (int i = 0; i < 4; i++){
    int n = n0 + i * 16 + l16;
#pragma unroll
    for (int r = 0; r < 4; r++){
      int m = m0 + wave * 16 + quad * 4 + r;
      if (m < M && n < N) C[(size_t)m * N + n] = (f16)acc[i][r];
    }
  }
}

// ---------------- attention coefficients (h fp16, att vectors fp32) ----------------

// H=4, C=64: one wave per node; lane owns channels 4l..4l+3 (head = l>>4)
__global__ __launch_bounds__(256) void attn4_k(const f16* __restrict__ h,
                                               const float* __restrict__ atts,
                                               const float* __restrict__ attd,
                                               float* __restrict__ a_s,
                                               float* __restrict__ a_d){
  int w = blockIdx.x * 4 + (threadIdx.x >> 6);
  if (w >= NN) return;
  int lane = threadIdx.x & 63;
  const half4 hv = *(const half4*)(h + (size_t)w * 256 + lane * 4);
  const f32x4 sv = *(const f32x4*)(atts + lane * 4);
  const f32x4 dv = *(const f32x4*)(attd + lane * 4);
  float h0 = (float)hv.x, h1 = (float)hv.y, h2 = (float)hv.z, h3 = (float)hv.w;
  float ps = h0 * sv.x + h1 * sv.y + h2 * sv.z + h3 * sv.w;
  float pd = h0 * dv.x + h1 * dv.y + h2 * dv.z + h3 * dv.w;
#pragma unroll
  for (int off = 8; off >= 1; off >>= 1){    // reduce within 16-lane head group
    ps += __shfl_xor(ps, off);
    pd += __shfl_xor(pd, off);
  }
  if ((lane & 15) == 0){
    a_s[w * 4 + (lane >> 4)] = ps;
    a_d[w * 4 + (lane >> 4)] = pd;
  }
}

// H=1, C=40
__global__ __launch_bounds__(256) void attn1_k(const f16* __restrict__ h,
                                               const float* __restrict__ atts,
                                               const float* __restrict__ attd,
                                               float* __restrict__ a_s,
                                               float* __restrict__ a_d){
  int w = blockIdx.x * 4 + (threadIdx.x >> 6);
  if (w >= NN) return;
  int lane = threadIdx.x & 63;
  float ps = 0.f, pd = 0.f;
  if (lane < 40){
    float hv = (float)h[(size_t)w * 40 + lane];
    ps = hv * atts[lane];
    pd = hv * attd[lane];
  }
#pragma unroll
  for (int off = 32; off >= 1; off >>= 1){
    ps += __shfl_xor(ps, off);
    pd += __shfl_xor(pd, off);
  }
  if (lane == 0){ a_s[w] = ps; a_d[w] = pd; }
}

// ---- edge softmax + aggregate: PAIRWISE online softmax, 2-deep prefetch -----------

__device__ __forceinline__ float lrelu(float e){ return e > 0.f ? e : 0.2f * e; }

// H=4, C=64 -> out[N,256](fp16) = ELU(softmax-agg + bias), feeds next GEMM
__global__ __launch_bounds__(256) void agg4_k(const f16* __restrict__ h,
                                              const float* __restrict__ a_s,
                                              const float* __restrict__ a_d,
                                              const int* __restrict__ row_ptr,
                                              const int* __restrict__ csr,
                                              const float* __restrict__ bias,
                                              f16* __restrict__ out){
  int w = blockIdx.x * 4 + (threadIdx.x >> 6);
  if (w >= NN) return;
  int lane = threadIdx.x & 63;
  int head = lane >> 4;
  float ad = a_d[w * 4 + head];
  int beg = row_ptr[w], end = row_ptr[w + 1];

  float m = -1e30f, denom = 0.f;
  float acc0 = 0.f, acc1 = 0.f, acc2 = 0.f, acc3 = 0.f;

  // preload first pair (clamped)
  int s0 = csr[beg];
  int s1 = csr[(beg + 1 < end) ? beg + 1 : beg];
  float e0 = a_s[s0 * 4 + head];
  float e1 = a_s[s1 * 4 + head];
  half4 h0 = *(const half4*)(h + (size_t)s0 * 256 + lane * 4);
  half4 h1 = *(const half4*)(h + (size_t)s1 * 256 + lane * 4);

  for (int j = beg; j < end; j += 2){
    // prefetch next pair (clamped to already-covered indices at the tail)
    int t0 = (j + 2 < end) ? j + 2 : j;
    int t1 = (j + 3 < end) ? j + 3 : j;
    int sp0 = csr[t0], sp1 = csr[t1];
    float ep0 = a_s[sp0 * 4 + head];
    float ep1 = a_s[sp1 * 4 + head];
    half4 hp0 = *(const half4*)(h + (size_t)sp0 * 256 + lane * 4);
    half4 hp1 = *(const half4*)(h + (size_t)sp1 * 256 + lane * 4);

    float ee0 = lrelu(e0 + ad);
    float ee1 = (j + 1 < end) ? lrelu(e1 + ad) : -1e30f;   // mask odd tail
    float mn = fmaxf(m, fmaxf(ee0, ee1));
    float cold = __expf(m - mn);                            // first iter: 0
    float al0 = __expf(ee0 - mn);
    float al1 = __expf(ee1 - mn);                           // masked -> 0
    denom = denom * cold + al0 + al1;
    acc0 = acc0 * cold + al0 * (float)h0.x + al1 * (float)h1.x;
    acc1 = acc1 * cold + al0 * (float)h0.y + al1 * (float)h1.y;
    acc2 = acc2 * cold + al0 * (float)h0.z + al1 * (float)h1.z;
    acc3 = acc3 * cold + al0 * (float)h0.w + al1 * (float)h1.w;
    m = mn;
    e0 = ep0; e1 = ep1; h0 = hp0; h1 = hp1;
  }

  float inv = 1.f / fmaxf(denom, 1e-30f);    // >=1 edge guaranteed (self-loop)
  float o0 = acc0 * inv + bias[lane * 4 + 0];
  float o1 = acc1 * inv + bias[lane * 4 + 1];
  float o2 = acc2 * inv + bias[lane * 4 + 2];
  float o3 = acc3 * inv + bias[lane * 4 + 3];
  o0 = o0 > 0.f ? o0 : __expf(o0) - 1.f;     // ELU
  o1 = o1 > 0.f ? o1 : __expf(o1) - 1.f;
  o2 = o2 > 0.f ? o2 : __expf(o2) - 1.f;
  o3 = o3 > 0.f ? o3 : __expf(o3) - 1.f;
  half4 r; r.x = (f16)o0; r.y = (f16)o1; r.z = (f16)o2; r.w = (f16)o3;
  *(half4*)(out + (size_t)w * 256 + lane * 4) = r;
}

// H=1, C=40 -> out[N,40](fp32) -> d_out, no ELU
__global__ __launch_bounds__(256) void agg1_k(const f16* __restrict__ h,
                                              const float* __restrict__ a_s,
                                              const float* __restrict__ a_d,
                                              const int* __restrict__ row_ptr,
                                              const int* __restrict__ csr,
                                              const float* __restrict__ bias,
                                              float* __restrict__ out){
  int w = blockIdx.x * 4 + (threadIdx.x >> 6);
  if (w >= NN) return;
  int lane = threadIdx.x & 63;
  int cl = (lane < 40) ? lane : 0;
  float ad = a_d[w];
  int beg = row_ptr[w], end = row_ptr[w + 1];

  float m = -1e30f, denom = 0.f, acc = 0.f;

  int s0 = csr[beg];
  int s1 = csr[(beg + 1 < end) ? beg + 1 : beg];
  float e0 = a_s[s0];
  float e1 = a_s[s1];
  float h0 = (float)h[(size_t)s0 * 40 + cl];
  float h1 = (float)h[(size_t)s1 * 40 + cl];

  for (int j = beg; j < end; j += 2){
    int t0 = (j + 2 < end) ? j + 2 : j;
    int t1 = (j + 3 < end) ? j + 3 : j;
    int sp0 = csr[t0], sp1 = csr[t1];
    float ep0 = a_s[sp0];
    float ep1 = a_s[sp1];
    float hp0 = (float)h[(size_t)sp0 * 40 + cl];
    float hp1 = (float)h[(size_t)sp1 * 40 + cl];

    float ee0 = lrelu(e0 + ad);
    float ee1 = (j + 1 < end) ? lrelu(e1 + ad) : -1e30f;
    float mn = fmaxf(m, fmaxf(ee0, ee1));
    float cold = __expf(m - mn);
    float al0 = __expf(ee0 - mn);
    float al1 = __expf(ee1 - mn);
    denom = denom * cold + al0 + al1;
    acc = acc * cold + al0 * h0 + al1 * h1;
    m = mn;
    e0 = ep0; e1 = ep1; h0 = hp0; h1 = hp1;
  }

  if (lane < 40){
    float o = acc / fmaxf(denom, 1e-30f) + bias[lane];
    out[(size_t)w * 40 + lane] = o;
  }
}

// ---------------- driver -----------------------------------------------------------

extern "C" void kernel_launch(void* const* d_in, const int* in_sizes, int n_in,
                              void* d_out, int out_size, void* d_ws, size_t ws_size,
                              hipStream_t stream){
  const float* x   = (const float*)d_in[0];
  const int*   ei  = (const int*)d_in[1];
  const float* W1  = (const float*)d_in[2];
  const float* as1 = (const float*)d_in[3];
  const float* ad1 = (const float*)d_in[4];
  const float* b1  = (const float*)d_in[5];
  const float* W2  = (const float*)d_in[6];
  const float* as2 = (const float*)d_in[7];
  const float* ad2 = (const float*)d_in[8];
  const float* b2  = (const float*)d_in[9];
  const float* W3  = (const float*)d_in[10];
  const float* as3 = (const float*)d_in[11];
  const float* ad3 = (const float*)d_in[12];
  const float* b3  = (const float*)d_in[13];

  const int E = in_sizes[1] / 2;             // 800000
  const int ETOT = E + NN;
  const int* src_arr = ei;
  const int* dst_arr = ei + E;

  char* ws = (char*)d_ws;
  size_t off = 0;
  auto alloc = [&](size_t bytes) -> void* {
    void* p = ws + off; off += (bytes + 255) & ~(size_t)255; return p;
  };
  int*   cnt     = (int*)  alloc((size_t)NN * 4);
  int*   row_ptr = (int*)  alloc((size_t)(NN + 1) * 4);
  int*   cursor  = (int*)  alloc((size_t)NN * 4);
  int*   csr     = (int*)  alloc((size_t)ETOT * 4);
  int*   bsum    = (int*)  alloc((size_t)256 * 4);
  int*   boff    = (int*)  alloc((size_t)256 * 4);
  f16*   W1t     = (f16*)  alloc((size_t)512 * 256 * 2);
  f16*   W2t     = (f16*)  alloc((size_t)256 * 256 * 2);
  f16*   W3t     = (f16*)  alloc((size_t)256 * 40 * 2);
  float* a_s     = (float*)alloc((size_t)NN * 4 * 4);
  float* a_d     = (float*)alloc((size_t)NN * 4 * 4);
  f16*   hbuf    = (f16*)  alloc((size_t)NN * 256 * 2);   // fp16 h (per-layer)
  f16*   xbuf    = (f16*)  alloc((size_t)NN * 256 * 2);   // fp16 inter-layer activations
  (void)ws_size; (void)n_in; (void)out_size;

  // CSR build (same graph reused by all 3 layers)
  hipMemsetAsync(cnt, 0, (size_t)NN * 4, stream);
  int egrid = (ETOT + 255) / 256;
  count_k    <<<egrid, 256, 0, stream>>>(dst_arr, cnt, E);
  scan_part_k<<<NB, 256, 0, stream>>>(cnt, bsum);
  scan_top_k <<<1, 256, 0, stream>>>(bsum, boff, row_ptr);
  scan_fin_k <<<NB, 256, 0, stream>>>(cnt, boff, row_ptr, cursor);
  scatter_k  <<<egrid, 256, 0, stream>>>(src_arr, dst_arr, cursor, csr, E);

  // weight transposes (fp32 -> fp16)
  transpose_k<<<(512 * 256 + 255) / 256, 256, 0, stream>>>(W1, W1t, 512, 256);
  transpose_k<<<(256 * 256 + 255) / 256, 256, 0, stream>>>(W2, W2t, 256, 256);
  transpose_k<<<(256 * 40  + 255) / 256, 256, 0, stream>>>(W3, W3t, 256, 40);

  dim3 blk(256);
  dim3 gT((NN + 127) / 128, 2);              // 128x128 tiles, N=256
  dim3 gC((NN + 63) / 64, 1);                // narrow GEMM layer 3 (N=40)
  int nodeblocks = (NN + 3) / 4;             // 12500, one wave per node

  // Layer 1: A = x (fp32), K=512
  gemm_tile_k<true> <<<gT, blk, 0, stream>>>(x, W1t, hbuf, NN, 256, 512);
  attn4_k<<<nodeblocks, blk, 0, stream>>>(hbuf, as1, ad1, a_s, a_d);
  agg4_k <<<nodeblocks, blk, 0, stream>>>(hbuf, a_s, a_d, row_ptr, csr, b1, xbuf);

  // Layer 2: A = xbuf (fp16), K=256
  gemm_tile_k<false><<<gT, blk, 0, stream>>>(xbuf, W2t, hbuf, NN, 256, 256);
  attn4_k<<<nodeblocks, blk, 0, stream>>>(hbuf, as2, ad2, a_s, a_d);
  agg4_k <<<nodeblocks, blk, 0, stream>>>(hbuf, a_s, a_d, row_ptr, csr, b2, xbuf);

  // Layer 3 (H=1, C=40) -> d_out (fp32)
  gemm_k<<<gC, blk, 0, stream>>>(xbuf, W3t, hbuf, NN, 40, 256);
  attn1_k<<<nodeblocks, blk, 0, stream>>>(hbuf, as3, ad3, a_s, a_d);
  agg1_k <<<nodeblocks, blk, 0, stream>>>(hbuf, a_s, a_d, row_ptr, csr, b3, (float*)d_out);
}